// Round 19
// baseline (305.340 us; speedup 1.0000x reference)
//
#include <hip/hip_runtime.h>
#include <hip/hip_bf16.h>

#define NB 512          // edge-pass blocks
#define MAXBKT 512      // supports n <= 131072
#define PB 4            // blocks per graph in fused agg3+pool

typedef __attribute__((ext_vector_type(8))) unsigned short ushort8;
typedef __attribute__((ext_vector_type(8))) short bf16x8;
typedef __attribute__((ext_vector_type(4))) float f32x4;

__device__ __forceinline__ unsigned short f2bf(float f) {
    unsigned u = __float_as_uint(f);
    unsigned r = (u + 0x7FFF + ((u >> 16) & 1)) >> 16;   // RNE
    return (unsigned short)r;
}

// ---- fused setup: [0,64) WT1, [64,128) WT2, [128,136) WLT=bf16(W3@Wlin)^T, rest: dst hist ----
__global__ __launch_bounds__(256) void k_wt3_hist(const float* __restrict__ W1,
                                                  const float* __restrict__ W2,
                                                  const float* __restrict__ W3,
                                                  const float* __restrict__ Wlin,
                                                  unsigned short* __restrict__ WT1,
                                                  unsigned short* __restrict__ WT2,
                                                  unsigned short* __restrict__ WLT,
                                                  const int* __restrict__ col, int E, int e2,
                                                  int per, int* __restrict__ cnt, int nbkt) {
    int b = blockIdx.x;
    if (b < 128) {
        const float* W = (b < 64) ? W1 : W2;
        unsigned short* WT = (b < 64) ? WT1 : WT2;
        int idx = (b & 63) * 256 + threadIdx.x;
        int nn = idx >> 7, k = idx & 127;
        WT[nn * 128 + k] = f2bf(W[k * 128 + nn]);
        return;
    }
    if (b < 136) {
        int idx = (b - 128) * 256 + threadIdx.x;     // 2048 total
        int c = idx >> 7, k = idx & 127;
        float s = 0.f;
        for (int j = 0; j < 128; ++j) s += W3[k * 128 + j] * Wlin[j * 16 + c];
        WLT[c * 128 + k] = f2bf(s);
        return;
    }
    int hb = b - 136;
    __shared__ int h[MAXBKT];
    int t = threadIdx.x;
    for (int i = t; i < nbkt; i += 256) h[i] = 0;
    __syncthreads();
    int s = hb * per, e = min(s + per, e2);
    for (int i = s + t; i < e; i += 256) {
        int dst = (i < E) ? col[i] : i - E;
        atomicAdd(&h[dst >> 8], 1);
    }
    __syncthreads();
    for (int i = t; i < nbkt; i += 256) cnt[i * NB + hb] = h[i];
}

// ---- hierarchical exclusive scan (2 kernels; bsum folded into consumers) ----
#define SCAN_T 256
#define SCAN_E 1024

__global__ void k_scan_a(const int* __restrict__ cnt, int n,
                         int* __restrict__ outp, int* __restrict__ bsum) {
    __shared__ int s[SCAN_T];
    int t = threadIdx.x, b = blockIdx.x;
    int base = b * SCAN_E + t * 4;
    int c0 = (base + 0 < n) ? cnt[base + 0] : 0;
    int c1 = (base + 1 < n) ? cnt[base + 1] : 0;
    int c2 = (base + 2 < n) ? cnt[base + 2] : 0;
    int c3 = (base + 3 < n) ? cnt[base + 3] : 0;
    int tsum = c0 + c1 + c2 + c3;
    s[t] = tsum; __syncthreads();
    for (int off = 1; off < SCAN_T; off <<= 1) {
        int v = (t >= off) ? s[t - off] : 0;
        __syncthreads();
        s[t] += v;
        __syncthreads();
    }
    int excl = s[t] - tsum;
    if (base + 0 < n) outp[base + 0] = excl;
    if (base + 1 < n) outp[base + 1] = excl + c0;
    if (base + 2 < n) outp[base + 2] = excl + c0 + c1;
    if (base + 3 < n) outp[base + 3] = excl + c0 + c1 + c2;
    if (t == 0) bsum[b] = s[SCAN_T - 1];
}

__global__ __launch_bounds__(256) void k_scan_b(int* __restrict__ bsum, int nb) {
    __shared__ int s[256];
    int t = threadIdx.x;
    int v = (t < nb) ? bsum[t] : 0;
    s[t] = v; __syncthreads();
    for (int off = 1; off < 256; off <<= 1) {
        int u = (t >= off) ? s[t - off] : 0;
        __syncthreads();
        s[t] += u;
        __syncthreads();
    }
    if (t < nb) bsum[t] = s[t] - v;   // exclusive
}

// ---- scatter edges to exact dst-bucket-major slots (zero global atomics) ----
__global__ __launch_bounds__(256) void k_scatter1(const int* __restrict__ row,
                                                  const int* __restrict__ col,
                                                  const float* __restrict__ ew,
                                                  int E, int e2, int per,
                                                  const int* __restrict__ S,
                                                  const int* __restrict__ bsum,
                                                  uint2* __restrict__ csrR, int nbkt) {
    __shared__ int cur[MAXBKT];
    int t = threadIdx.x;
    for (int i = t; i < nbkt; i += 256) {
        int idx = i * NB + blockIdx.x;
        cur[i] = S[idx] + bsum[idx >> 10];
    }
    __syncthreads();
    int s = blockIdx.x * per, e = min(s + per, e2);
    for (int i = s + t; i < e; i += 256) {
        int src, dst; float w;
        if (i < E) { src = row[i]; dst = col[i]; w = ew[i]; }
        else       { src = dst = i - E; w = 1.0f; }
        int slot = atomicAdd(&cur[dst >> 8], 1);
        csrR[slot] = make_uint2(((unsigned)src << 8) | (unsigned)(dst & 255),
                                __float_as_uint(w));
    }
}

// ---- per-bucket regroup by dst; emits dinv, rowptr, final CSR, and bucket-local
//      degree-sorted perm (dense: perm[i] valid for all i < n) ----
__global__ __launch_bounds__(256) void k_build(const uint2* __restrict__ csrR,
                                               const int* __restrict__ S,
                                               const int* __restrict__ bsum,
                                               int n, int e2,
                                               float2* __restrict__ csrF,
                                               float* __restrict__ dinv,
                                               int* __restrict__ rowptr,
                                               int* __restrict__ perm, int nbkt) {
    __shared__ int   cnt[256];
    __shared__ float wsm[256];
    __shared__ int   off[256];
    __shared__ float dvs[256];
    __shared__ int   curs[256];
    __shared__ int   h64[64];
    int b = blockIdx.x, t = threadIdx.x;
    cnt[t] = 0; wsm[t] = 0.f;
    __syncthreads();
    int i0 = b * NB;
    int base = S[i0] + bsum[i0 >> 10];
    int end;
    if (b + 1 < nbkt) { int i1 = (b + 1) * NB; end = S[i1] + bsum[i1 >> 10]; }
    else end = e2;
    for (int i = base + t; i < end; i += 256) {
        uint2 r = csrR[i];
        int d = r.x & 255;
        atomicAdd(&cnt[d], 1);
        atomicAdd(&wsm[d], __uint_as_float(r.y));
    }
    __syncthreads();
    int   myc = cnt[t];
    float w   = wsm[t];
    float dv  = (w > 0.f) ? rsqrtf(w) : 0.f;
    dvs[t] = dv;
    off[t] = myc;
    __syncthreads();
    for (int o = 1; o < 256; o <<= 1) {
        int v = (t >= o) ? off[t - o] : 0;
        __syncthreads();
        off[t] += v;
        __syncthreads();
    }
    int excl = off[t] - myc;
    int node = b * 256 + t;
    bool valid = node < n;
    if (valid) { dinv[node] = dv; rowptr[node] = base + excl; }
    if (b == nbkt - 1 && t == 0) rowptr[n] = e2;
    curs[t] = excl;
    __syncthreads();
    for (int i = base + t; i < end; i += 256) {
        uint2 r = csrR[i];
        int d = r.x & 255;
        int src = (int)(r.x >> 8);
        int p = base + atomicAdd(&curs[d], 1);
        csrF[p] = make_float2(__int_as_float(src), __uint_as_float(r.y) * dvs[d]);
    }
    // ---- bucket-local degree counting-sort -> perm (no extra launches) ----
    if (t < 64) h64[t] = 0;
    __syncthreads();
    int db = min(myc, 63);
    if (valid) atomicAdd(&h64[db], 1);
    __syncthreads();
    int hv = (t < 64) ? h64[t] : 0;
    off[t] = hv;
    __syncthreads();
    for (int o = 1; o < 64; o <<= 1) {
        int u = (t >= o && t < 64) ? off[t - o] : 0;
        __syncthreads();
        if (t < 64) off[t] += u;
        __syncthreads();
    }
    if (t < 64) h64[t] = off[t] - hv;   // exclusive base cursors
    __syncthreads();
    if (valid) {
        int slot = atomicAdd(&h64[db], 1);
        perm[b * 256 + slot] = node;
    }
}

// ---- MFMA GEMM (layer 1): O[r] = bf16((x@W1)[r] * dinv[r]), node-major out ----
__global__ __launch_bounds__(256) void k_gemm_mfma(const float* __restrict__ H,
                                                   const unsigned short* __restrict__ WT,
                                                   const float* __restrict__ dinv,
                                                   unsigned short* __restrict__ O, int n) {
    int wv = threadIdx.x >> 6, lane = threadIdx.x & 63;
    int rowBase = blockIdx.x * 64 + wv * 16;
    int lr = lane & 15;
    int lk = (lane >> 4) * 8;

    int arow = min(rowBase + lr, n - 1);
    bf16x8 a[4];
#pragma unroll
    for (int kk = 0; kk < 4; ++kk) {
        const float4* p = (const float4*)&H[(size_t)arow * 128 + kk * 32 + lk];
        float4 h0 = p[0], h1 = p[1];
        bf16x8 av;
        av[0] = (short)f2bf(h0.x); av[1] = (short)f2bf(h0.y);
        av[2] = (short)f2bf(h0.z); av[3] = (short)f2bf(h0.w);
        av[4] = (short)f2bf(h1.x); av[5] = (short)f2bf(h1.y);
        av[6] = (short)f2bf(h1.z); av[7] = (short)f2bf(h1.w);
        a[kk] = av;
    }

    f32x4 acc[8] = {};
#pragma unroll
    for (int c = 0; c < 8; ++c) {
#pragma unroll
        for (int kk = 0; kk < 4; ++kk) {
            bf16x8 b = *(const bf16x8*)&WT[(size_t)(c * 16 + lr) * 128 + kk * 32 + lk];
            acc[c] = __builtin_amdgcn_mfma_f32_16x16x32_bf16(a[kk], b, acc[c], 0, 0, 0);
        }
    }

#pragma unroll
    for (int r = 0; r < 4; ++r) {
        int node = rowBase + (lane >> 4) * 4 + r;
        if (node < n) {
            float sc = dinv[node];
#pragma unroll
            for (int c = 0; c < 8; ++c)
                O[(size_t)node * 128 + c * 16 + lr] = f2bf(acc[c][r] * sc);
        }
    }
}

// ---- shared agg phase (bucket-degree-sorted): 16 lanes/node, 4 nodes/wave, fp32 accum ----
#define AGG_BODY(BIAS)                                                          \
    int t = threadIdx.x;                                                        \
    int wv = t >> 6, lane = t & 63;                                             \
    int g = lane >> 4, sl = lane & 15;                                          \
    int slot = blockIdx.x * 16 + wv * 4 + g;                                    \
    int s = 0, e = 0;                                                           \
    if (slot < n) { int nd = perm[slot]; s = rowptr[nd]; e = rowptr[nd + 1]; }  \
    float a0 = 0.f, a1 = 0.f, a2 = 0.f, a3 = 0.f,                               \
          a4 = 0.f, a5 = 0.f, a6 = 0.f, a7 = 0.f;                               \
    int i = s;                                                                  \
    for (; i + 2 <= e; i += 2) {                                                \
        float2 p0 = csr[i], p1 = csr[i + 1];                                    \
        uint4 v0 = Hw[(size_t)__float_as_int(p0.x) * 16 + sl];                  \
        uint4 v1 = Hw[(size_t)__float_as_int(p1.x) * 16 + sl];                  \
        FMA8(v0, p0.y); FMA8(v1, p1.y);                                         \
    }                                                                           \
    if (i < e) {                                                                \
        float2 pp = csr[i];                                                     \
        uint4 v = Hw[(size_t)__float_as_int(pp.x) * 16 + sl];                   \
        FMA8(v, pp.y);                                                          \
    }                                                                           \
    const float4* b4 = (const float4*)&(BIAS)[sl * 8];                          \
    float4 bb0 = b4[0], bb1 = b4[1];                                            \
    a0 = fmaxf(a0 + bb0.x, 0.f); a1 = fmaxf(a1 + bb0.y, 0.f);                   \
    a2 = fmaxf(a2 + bb0.z, 0.f); a3 = fmaxf(a3 + bb0.w, 0.f);                   \
    a4 = fmaxf(a4 + bb1.x, 0.f); a5 = fmaxf(a5 + bb1.y, 0.f);                   \
    a6 = fmaxf(a6 + bb1.z, 0.f); a7 = fmaxf(a7 + bb1.w, 0.f);                   \
    ushort8 o;                                                                  \
    o[0] = f2bf(a0); o[1] = f2bf(a1); o[2] = f2bf(a2); o[3] = f2bf(a3);         \
    o[4] = f2bf(a4); o[5] = f2bf(a5); o[6] = f2bf(a6); o[7] = f2bf(a7);         \
    *(ushort8*)&lds[wv * 4 + g][sl * 8] = o;                                    \
    __syncthreads();

#define FMA8(V, W8) do {                                              \
    float _w = (W8);                                                  \
    a0 += __uint_as_float((V).x << 16) * _w;                          \
    a1 += __uint_as_float((V).x & 0xFFFF0000u) * _w;                  \
    a2 += __uint_as_float((V).y << 16) * _w;                          \
    a3 += __uint_as_float((V).y & 0xFFFF0000u) * _w;                  \
    a4 += __uint_as_float((V).z << 16) * _w;                          \
    a5 += __uint_as_float((V).z & 0xFFFF0000u) * _w;                  \
    a6 += __uint_as_float((V).w << 16) * _w;                          \
    a7 += __uint_as_float((V).w & 0xFFFF0000u) * _w;                  \
} while (0)

// ---- fused agg1(+b1+relu) -> LDS -> @WT2 * dinv -> bf16 m2 (16-node block, 4.2KB LDS) ----
__global__ __launch_bounds__(256) void k_agg_gemm(const uint4* __restrict__ Hw,
                                                  const int* __restrict__ rowptr,
                                                  const int* __restrict__ perm,
                                                  const float2* __restrict__ csr,
                                                  const float* __restrict__ bias,
                                                  const unsigned short* __restrict__ WT,
                                                  const float* __restrict__ dinv,
                                                  unsigned short* __restrict__ O, int n) {
    __shared__ __align__(16) unsigned short lds[16][132];
    AGG_BODY(bias)
    // GEMM phase: wave wv computes column-tiles {2wv, 2wv+1} of the 16x128 output
    int lr = lane & 15;
    int lk = (lane >> 4) * 8;
    bf16x8 a[4];
#pragma unroll
    for (int kk = 0; kk < 4; ++kk)
        a[kk] = *(const bf16x8*)&lds[lr][kk * 32 + lk];
    f32x4 acc[2] = {};
#pragma unroll
    for (int c2 = 0; c2 < 2; ++c2) {
        int c = wv * 2 + c2;
#pragma unroll
        for (int kk = 0; kk < 4; ++kk) {
            bf16x8 b = *(const bf16x8*)&WT[(size_t)(c * 16 + lr) * 128 + kk * 32 + lk];
            acc[c2] = __builtin_amdgcn_mfma_f32_16x16x32_bf16(a[kk], b, acc[c2], 0, 0, 0);
        }
    }
#pragma unroll
    for (int r = 0; r < 4; ++r) {
        int slot2 = blockIdx.x * 16 + (lane >> 4) * 4 + r;
        if (slot2 < n) {
            int n2 = perm[slot2];
            float sc = dinv[n2];
            O[(size_t)n2 * 128 + (wv * 2 + 0) * 16 + lr] = f2bf(acc[0][r] * sc);
            O[(size_t)n2 * 128 + (wv * 2 + 1) * 16 + lr] = f2bf(acc[1][r] * sc);
        }
    }
}

// ---- fused agg2(+b2+relu) -> LDS -> @WLT * dinv -> fp32 P[n][16] (wave 0 does the tile) ----
__global__ __launch_bounds__(256) void k_agg_gemmP(const uint4* __restrict__ Hw,
                                                   const int* __restrict__ rowptr,
                                                   const int* __restrict__ perm,
                                                   const float2* __restrict__ csr,
                                                   const float* __restrict__ bias,
                                                   const unsigned short* __restrict__ WLT,
                                                   const float* __restrict__ dinv,
                                                   float* __restrict__ P, int n) {
    __shared__ __align__(16) unsigned short lds[16][132];
    AGG_BODY(bias)
    if (wv == 0) {
        int lr = lane & 15;
        int lk = (lane >> 4) * 8;
        f32x4 acc = {};
#pragma unroll
        for (int kk = 0; kk < 4; ++kk) {
            bf16x8 a = *(const bf16x8*)&lds[lr][kk * 32 + lk];
            bf16x8 b = *(const bf16x8*)&WLT[(size_t)lr * 128 + kk * 32 + lk];
            acc = __builtin_amdgcn_mfma_f32_16x16x32_bf16(a, b, acc, 0, 0, 0);
        }
#pragma unroll
        for (int r = 0; r < 4; ++r) {
            int slot2 = blockIdx.x * 16 + (lane >> 4) * 4 + r;
            if (slot2 < n) {
                int n2 = perm[slot2];
                P[(size_t)n2 * 16 + lr] = acc[r] * dinv[n2];
            }
        }
    }
}
#undef FMA8
#undef AGG_BODY

// ---------------- fused layer-3 agg + pool (linear path): per-graph edge-sum of P ----------------
__device__ __forceinline__ int lower_bound_i(const int* a, int n, int key) {
    int lo = 0, hi = n;
    while (lo < hi) { int mid = (lo + hi) >> 1; if (a[mid] < key) lo = mid + 1; else hi = mid; }
    return lo;
}

__global__ __launch_bounds__(256) void k_agg_pool(const float4* __restrict__ P4,
                                                  const int* __restrict__ rowptr,
                                                  const float2* __restrict__ csr,
                                                  const int* __restrict__ batch,
                                                  int n, float* __restrict__ partial) {
    int g = blockIdx.x >> 2, part = blockIdx.x & (PB - 1);
    int start = lower_bound_i(batch, n, g);
    int end   = lower_bound_i(batch, n, g + 1);
    int cn = end - start;
    int ns = start + (cn * part) / PB;
    int ne = start + (cn * (part + 1)) / PB;
    int es = rowptr[ns], ee = rowptr[ne];
    int t = threadIdx.x, grp = t >> 2, sl4 = t & 3;   // 64 groups x 4 lanes
    float a0 = 0.f, a1 = 0.f, a2 = 0.f, a3 = 0.f;
    int i = es + grp;
    for (; i + 64 < ee; i += 128) {
        float2 p0 = csr[i], p1 = csr[i + 64];
        float4 v0 = P4[(size_t)__float_as_int(p0.x) * 4 + sl4];
        float4 v1 = P4[(size_t)__float_as_int(p1.x) * 4 + sl4];
        a0 += v0.x * p0.y; a1 += v0.y * p0.y; a2 += v0.z * p0.y; a3 += v0.w * p0.y;
        a0 += v1.x * p1.y; a1 += v1.y * p1.y; a2 += v1.z * p1.y; a3 += v1.w * p1.y;
    }
    if (i < ee) {
        float2 pp = csr[i];
        float4 v = P4[(size_t)__float_as_int(pp.x) * 4 + sl4];
        a0 += v.x * pp.y; a1 += v.y * pp.y; a2 += v.z * pp.y; a3 += v.w * pp.y;
    }
    __shared__ float red[64][20];
    *(float4*)&red[grp][sl4 * 4] = make_float4(a0, a1, a2, a3);
    __syncthreads();
    if (t < 16) {
        float s = 0.f;
        for (int k2 = 0; k2 < 64; ++k2) s += red[k2][t];
        partial[(size_t)blockIdx.x * 16 + t] = s;
    }
}

// final: reduce PB partials, /cnt, + b3@Wlin + blin
__global__ void k_poolfin(const float* __restrict__ partial, const int* __restrict__ batch,
                          const float* __restrict__ b3, const float* __restrict__ Wlin,
                          const float* __restrict__ blin, float* __restrict__ out, int n) {
    int g = blockIdx.x, t = threadIdx.x;
    if (t >= 16) return;
    int start = lower_bound_i(batch, n, g);
    int end   = lower_bound_i(batch, n, g + 1);
    int cn = end - start;
    float s = partial[(size_t)(g * PB + 0) * 16 + t] + partial[(size_t)(g * PB + 1) * 16 + t]
            + partial[(size_t)(g * PB + 2) * 16 + t] + partial[(size_t)(g * PB + 3) * 16 + t];
    float bw = 0.f;
    for (int ch = 0; ch < 128; ++ch) bw += b3[ch] * Wlin[ch * 16 + t];
    out[g * 16 + t] = (cn > 0) ? s / (float)cn + bw + blin[t] : blin[t];
}

// ---------------- host ----------------
extern "C" void kernel_launch(void* const* d_in, const int* in_sizes, int n_in,
                              void* d_out, int out_size, void* d_ws, size_t ws_size,
                              hipStream_t stream) {
    const float* x    = (const float*)d_in[0];
    const int*   ei   = (const int*)d_in[1];
    const float* ew   = (const float*)d_in[2];
    const int*   batch= (const int*)d_in[3];
    const float* W1   = (const float*)d_in[4];
    const float* b1   = (const float*)d_in[5];
    const float* W2   = (const float*)d_in[6];
    const float* b2   = (const float*)d_in[7];
    const float* W3   = (const float*)d_in[8];
    const float* b3   = (const float*)d_in[9];
    const float* Wlin = (const float*)d_in[10];
    const float* blin = (const float*)d_in[11];
    float* out = (float*)d_out;

    int n  = in_sizes[0] / 128;
    int E  = in_sizes[2];
    int e2 = E + n;
    int G  = out_size / 16;
    const int* row = ei;
    const int* col = ei + E;

    int nbkt = (n + 255) >> 8;          // 256 nodes per bucket
    int M    = nbkt * NB;

    char* ws = (char*)d_ws;
    size_t off = 0;
    auto alloc = [&](size_t bytes) -> void* {
        void* p = ws + off;
        off = (off + bytes + 255) & ~255UL;
        return p;
    };
    // regionA: csrR (e2*8B) during pre; bf16 m2 (n*256B) after k_build
    size_t rawBytes = (size_t)e2 * 8;
    size_t hBytes   = (size_t)n * 128 * 2;
    void* regionA = alloc(rawBytes > hBytes ? rawBytes : hBytes);
    uint2*  csrR  = (uint2*)regionA;
    unsigned short* bufM2 = (unsigned short*)regionA;       // aliases csrR after k_build
    unsigned short* bufM1 = (unsigned short*)alloc((size_t)n * 128 * 2);
    float2* csrF  = (float2*)alloc((size_t)e2 * 8);
    int*    cntA  = (int*)  alloc((size_t)M * 4);
    int*    S     = (int*)  alloc((size_t)M * 4);
    int*    bsum  = (int*)  alloc(4096);
    float*  dinv  = (float*)alloc((size_t)n * 4);
    int*    rowptr= (int*)  alloc((size_t)(n + 1) * 4);
    int*    perm  = (int*)  alloc((size_t)nbkt * 256 * 4);
    unsigned short* WT1 = (unsigned short*)alloc(128 * 128 * 2);
    unsigned short* WT2 = (unsigned short*)alloc(128 * 128 * 2);
    unsigned short* WLT = (unsigned short*)alloc(16 * 128 * 2);
    float*  P       = (float*)alloc((size_t)n * 16 * 4);
    float*  partial = (float*)alloc((size_t)G * PB * 16 * 4);
    (void)ws_size;

    int per = (e2 + NB - 1) / NB;
    int nbScan = (M + SCAN_E - 1) / SCAN_E;   // <= 256 for n <= 131072

    // fused weight prep + dst histogram (all independent)
    k_wt3_hist<<<136 + NB, 256, 0, stream>>>(W1, W2, W3, Wlin, WT1, WT2, WLT,
                                             col, E, e2, per, cntA, nbkt);
    k_scan_a<<<nbScan, SCAN_T, 0, stream>>>(cntA, M, S, bsum);
    k_scan_b<<<1, 256, 0, stream>>>(bsum, nbScan);
    k_scatter1<<<NB, 256, 0, stream>>>(row, col, ew, E, e2, per, S, bsum, csrR, nbkt);
    k_build<<<nbkt, 256, 0, stream>>>(csrR, S, bsum, n, e2, csrF, dinv, rowptr, perm, nbkt);

    int gb = (n + 63) / 64;
    int ab = (n + 15) / 16;
    k_gemm_mfma<<<gb, 256, 0, stream>>>(x, WT1, dinv, bufM1, n);
    k_agg_gemm<<<ab, 256, 0, stream>>>((const uint4*)bufM1, rowptr, perm, csrF, b1, WT2, dinv, bufM2, n);
    k_agg_gemmP<<<ab, 256, 0, stream>>>((const uint4*)bufM2, rowptr, perm, csrF, b2, WLT, dinv, P, n);
    k_agg_pool<<<G * PB, 256, 0, stream>>>((const float4*)P, rowptr, csrF, batch, n, partial);
    k_poolfin<<<G, 64, 0, stream>>>(partial, batch, b3, Wlin, blin, out, n);
}

// Round 20
// 279.587 us; speedup vs baseline: 1.0921x; 1.0921x over previous
//
#include <hip/hip_runtime.h>
#include <hip/hip_bf16.h>

#define NB 512          // edge-pass blocks
#define MAXBKT 512      // supports n <= 131072
#define PB 4            // blocks per graph in fused agg3+pool

typedef __attribute__((ext_vector_type(8))) unsigned short ushort8;
typedef __attribute__((ext_vector_type(8))) short bf16x8;
typedef __attribute__((ext_vector_type(4))) float f32x4;

__device__ __forceinline__ unsigned short f2bf(float f) {
    unsigned u = __float_as_uint(f);
    unsigned r = (u + 0x7FFF + ((u >> 16) & 1)) >> 16;   // RNE
    return (unsigned short)r;
}

// ---- fused setup: [0,64) WT1, [64,128) WT2, [128,136) WLT=bf16(W3@Wlin)^T, rest: dst hist ----
__global__ __launch_bounds__(256) void k_wt3_hist(const float* __restrict__ W1,
                                                  const float* __restrict__ W2,
                                                  const float* __restrict__ W3,
                                                  const float* __restrict__ Wlin,
                                                  unsigned short* __restrict__ WT1,
                                                  unsigned short* __restrict__ WT2,
                                                  unsigned short* __restrict__ WLT,
                                                  const int* __restrict__ col, int E, int e2,
                                                  int per, int* __restrict__ cnt, int nbkt) {
    int b = blockIdx.x;
    if (b < 128) {
        const float* W = (b < 64) ? W1 : W2;
        unsigned short* WT = (b < 64) ? WT1 : WT2;
        int idx = (b & 63) * 256 + threadIdx.x;
        int nn = idx >> 7, k = idx & 127;
        WT[nn * 128 + k] = f2bf(W[k * 128 + nn]);
        return;
    }
    if (b < 136) {
        // WLT[c*128 + k] = bf16( sum_j W3[k][j] * Wlin[j][c] ), c<16, k<128
        int idx = (b - 128) * 256 + threadIdx.x;     // 2048 total
        int c = idx >> 7, k = idx & 127;
        float s = 0.f;
        for (int j = 0; j < 128; ++j) s += W3[k * 128 + j] * Wlin[j * 16 + c];
        WLT[c * 128 + k] = f2bf(s);
        return;
    }
    int hb = b - 136;
    __shared__ int h[MAXBKT];
    int t = threadIdx.x;
    for (int i = t; i < nbkt; i += 256) h[i] = 0;
    __syncthreads();
    int s = hb * per, e = min(s + per, e2);
    for (int i = s + t; i < e; i += 256) {
        int dst = (i < E) ? col[i] : i - E;
        atomicAdd(&h[dst >> 8], 1);
    }
    __syncthreads();
    for (int i = t; i < nbkt; i += 256) cnt[i * NB + hb] = h[i];
}

// ---- hierarchical exclusive scan (2 kernels; bsum folded into consumers) ----
#define SCAN_T 256
#define SCAN_E 1024

__global__ void k_scan_a(const int* __restrict__ cnt, int n,
                         int* __restrict__ outp, int* __restrict__ bsum) {
    __shared__ int s[SCAN_T];
    int t = threadIdx.x, b = blockIdx.x;
    int base = b * SCAN_E + t * 4;
    int c0 = (base + 0 < n) ? cnt[base + 0] : 0;
    int c1 = (base + 1 < n) ? cnt[base + 1] : 0;
    int c2 = (base + 2 < n) ? cnt[base + 2] : 0;
    int c3 = (base + 3 < n) ? cnt[base + 3] : 0;
    int tsum = c0 + c1 + c2 + c3;
    s[t] = tsum; __syncthreads();
    for (int off = 1; off < SCAN_T; off <<= 1) {
        int v = (t >= off) ? s[t - off] : 0;
        __syncthreads();
        s[t] += v;
        __syncthreads();
    }
    int excl = s[t] - tsum;
    if (base + 0 < n) outp[base + 0] = excl;
    if (base + 1 < n) outp[base + 1] = excl + c0;
    if (base + 2 < n) outp[base + 2] = excl + c0 + c1;
    if (base + 3 < n) outp[base + 3] = excl + c0 + c1 + c2;
    if (t == 0) bsum[b] = s[SCAN_T - 1];
}

__global__ __launch_bounds__(256) void k_scan_b(int* __restrict__ bsum, int nb) {
    __shared__ int s[256];
    int t = threadIdx.x;
    int v = (t < nb) ? bsum[t] : 0;
    s[t] = v; __syncthreads();
    for (int off = 1; off < 256; off <<= 1) {
        int u = (t >= off) ? s[t - off] : 0;
        __syncthreads();
        s[t] += u;
        __syncthreads();
    }
    if (t < nb) bsum[t] = s[t] - v;   // exclusive
}

// ---- scatter edges to exact dst-bucket-major slots (zero global atomics) ----
__global__ __launch_bounds__(256) void k_scatter1(const int* __restrict__ row,
                                                  const int* __restrict__ col,
                                                  const float* __restrict__ ew,
                                                  int E, int e2, int per,
                                                  const int* __restrict__ S,
                                                  const int* __restrict__ bsum,
                                                  uint2* __restrict__ csrR, int nbkt) {
    __shared__ int cur[MAXBKT];
    int t = threadIdx.x;
    for (int i = t; i < nbkt; i += 256) {
        int idx = i * NB + blockIdx.x;
        cur[i] = S[idx] + bsum[idx >> 10];
    }
    __syncthreads();
    int s = blockIdx.x * per, e = min(s + per, e2);
    for (int i = s + t; i < e; i += 256) {
        int src, dst; float w;
        if (i < E) { src = row[i]; dst = col[i]; w = ew[i]; }
        else       { src = dst = i - E; w = 1.0f; }
        int slot = atomicAdd(&cur[dst >> 8], 1);
        csrR[slot] = make_uint2(((unsigned)src << 8) | (unsigned)(dst & 255),
                                __float_as_uint(w));
    }
}

// ---- per-bucket regroup by dst; emits dinv, rowptr, final CSR ----
__global__ __launch_bounds__(256) void k_build(const uint2* __restrict__ csrR,
                                               const int* __restrict__ S,
                                               const int* __restrict__ bsum,
                                               int n, int e2,
                                               float2* __restrict__ csrF,
                                               float* __restrict__ dinv,
                                               int* __restrict__ rowptr, int nbkt) {
    __shared__ int   cnt[256];
    __shared__ float wsm[256];
    __shared__ int   off[256];
    __shared__ float dvs[256];
    __shared__ int   curs[256];
    int b = blockIdx.x, t = threadIdx.x;
    cnt[t] = 0; wsm[t] = 0.f;
    __syncthreads();
    int i0 = b * NB;
    int base = S[i0] + bsum[i0 >> 10];
    int end;
    if (b + 1 < nbkt) { int i1 = (b + 1) * NB; end = S[i1] + bsum[i1 >> 10]; }
    else end = e2;
    for (int i = base + t; i < end; i += 256) {
        uint2 r = csrR[i];
        int d = r.x & 255;
        atomicAdd(&cnt[d], 1);
        atomicAdd(&wsm[d], __uint_as_float(r.y));
    }
    __syncthreads();
    int   myc = cnt[t];
    float w   = wsm[t];
    float dv  = (w > 0.f) ? rsqrtf(w) : 0.f;
    dvs[t] = dv;
    off[t] = myc;
    __syncthreads();
    for (int o = 1; o < 256; o <<= 1) {
        int v = (t >= o) ? off[t - o] : 0;
        __syncthreads();
        off[t] += v;
        __syncthreads();
    }
    int excl = off[t] - myc;
    int node = b * 256 + t;
    if (node < n) { dinv[node] = dv; rowptr[node] = base + excl; }
    if (b == nbkt - 1 && t == 0) rowptr[n] = e2;
    curs[t] = excl;
    __syncthreads();
    for (int i = base + t; i < end; i += 256) {
        uint2 r = csrR[i];
        int d = r.x & 255;
        int src = (int)(r.x >> 8);
        int p = base + atomicAdd(&curs[d], 1);
        csrF[p] = make_float2(__int_as_float(src), __uint_as_float(r.y) * dvs[d]);
    }
}

// ---- MFMA GEMM (layer 1): O[r] = bf16((x@W1)[r] * dinv[r]) ----
__global__ __launch_bounds__(256) void k_gemm_mfma(const float* __restrict__ H,
                                                   const unsigned short* __restrict__ WT,
                                                   const float* __restrict__ dinv,
                                                   unsigned short* __restrict__ O, int n) {
    int wv = threadIdx.x >> 6, lane = threadIdx.x & 63;
    int rowBase = blockIdx.x * 64 + wv * 16;
    int lr = lane & 15;
    int lk = (lane >> 4) * 8;

    int arow = min(rowBase + lr, n - 1);
    bf16x8 a[4];
#pragma unroll
    for (int kk = 0; kk < 4; ++kk) {
        const float4* p = (const float4*)&H[(size_t)arow * 128 + kk * 32 + lk];
        float4 h0 = p[0], h1 = p[1];
        bf16x8 av;
        av[0] = (short)f2bf(h0.x); av[1] = (short)f2bf(h0.y);
        av[2] = (short)f2bf(h0.z); av[3] = (short)f2bf(h0.w);
        av[4] = (short)f2bf(h1.x); av[5] = (short)f2bf(h1.y);
        av[6] = (short)f2bf(h1.z); av[7] = (short)f2bf(h1.w);
        a[kk] = av;
    }

    f32x4 acc[8] = {};
#pragma unroll
    for (int c = 0; c < 8; ++c) {
#pragma unroll
        for (int kk = 0; kk < 4; ++kk) {
            bf16x8 b = *(const bf16x8*)&WT[(size_t)(c * 16 + lr) * 128 + kk * 32 + lk];
            acc[c] = __builtin_amdgcn_mfma_f32_16x16x32_bf16(a[kk], b, acc[c], 0, 0, 0);
        }
    }

#pragma unroll
    for (int r = 0; r < 4; ++r) {
        int node = rowBase + (lane >> 4) * 4 + r;
        if (node < n) {
            float sc = dinv[node];
#pragma unroll
            for (int c = 0; c < 8; ++c)
                O[(size_t)node * 128 + c * 16 + lr] = f2bf(acc[c][r] * sc);
        }
    }
}

// ---- shared agg phase macro body (16 lanes/node, 4 nodes/wave, fp32 accum) ----
#define AGG_BODY(BIAS)                                                          \
    int t = threadIdx.x;                                                        \
    int wv = t >> 6, lane = t & 63;                                             \
    int g = lane >> 4, sl = lane & 15;                                          \
    int node = blockIdx.x * 16 + wv * 4 + g;                                    \
    int s = 0, e = 0;                                                           \
    if (node < n) { s = rowptr[node]; e = rowptr[node + 1]; }                   \
    float a0 = 0.f, a1 = 0.f, a2 = 0.f, a3 = 0.f,                               \
          a4 = 0.f, a5 = 0.f, a6 = 0.f, a7 = 0.f;                               \
    int i = s;                                                                  \
    for (; i + 2 <= e; i += 2) {                                                \
        float2 p0 = csr[i], p1 = csr[i + 1];                                    \
        uint4 v0 = Hw[(size_t)__float_as_int(p0.x) * 16 + sl];                  \
        uint4 v1 = Hw[(size_t)__float_as_int(p1.x) * 16 + sl];                  \
        FMA8(v0, p0.y); FMA8(v1, p1.y);                                         \
    }                                                                           \
    if (i < e) {                                                                \
        float2 pp = csr[i];                                                     \
        uint4 v = Hw[(size_t)__float_as_int(pp.x) * 16 + sl];                   \
        FMA8(v, pp.y);                                                          \
    }                                                                           \
    const float4* b4 = (const float4*)&(BIAS)[sl * 8];                          \
    float4 bb0 = b4[0], bb1 = b4[1];                                            \
    a0 = fmaxf(a0 + bb0.x, 0.f); a1 = fmaxf(a1 + bb0.y, 0.f);                   \
    a2 = fmaxf(a2 + bb0.z, 0.f); a3 = fmaxf(a3 + bb0.w, 0.f);                   \
    a4 = fmaxf(a4 + bb1.x, 0.f); a5 = fmaxf(a5 + bb1.y, 0.f);                   \
    a6 = fmaxf(a6 + bb1.z, 0.f); a7 = fmaxf(a7 + bb1.w, 0.f);                   \
    ushort8 o;                                                                  \
    o[0] = f2bf(a0); o[1] = f2bf(a1); o[2] = f2bf(a2); o[3] = f2bf(a3);         \
    o[4] = f2bf(a4); o[5] = f2bf(a5); o[6] = f2bf(a6); o[7] = f2bf(a7);         \
    *(ushort8*)&lds[wv * 4 + g][sl * 8] = o;                                    \
    __syncthreads();

#define FMA8(V, W8) do {                                              \
    float _w = (W8);                                                  \
    a0 += __uint_as_float((V).x << 16) * _w;                          \
    a1 += __uint_as_float((V).x & 0xFFFF0000u) * _w;                  \
    a2 += __uint_as_float((V).y << 16) * _w;                          \
    a3 += __uint_as_float((V).y & 0xFFFF0000u) * _w;                  \
    a4 += __uint_as_float((V).z << 16) * _w;                          \
    a5 += __uint_as_float((V).z & 0xFFFF0000u) * _w;                  \
    a6 += __uint_as_float((V).w << 16) * _w;                          \
    a7 += __uint_as_float((V).w & 0xFFFF0000u) * _w;                  \
} while (0)

// ---- fused agg1(+b1+relu) -> LDS -> @WT2 * dinv -> bf16 m2 (16-node block, 4.2KB LDS) ----
__global__ __launch_bounds__(256) void k_agg_gemm(const uint4* __restrict__ Hw,
                                                  const int* __restrict__ rowptr,
                                                  const float2* __restrict__ csr,
                                                  const float* __restrict__ bias,
                                                  const unsigned short* __restrict__ WT,
                                                  const float* __restrict__ dinv,
                                                  unsigned short* __restrict__ O, int n) {
    __shared__ __align__(16) unsigned short lds[16][132];
    AGG_BODY(bias)
    // GEMM phase: wave wv computes column-tiles {2wv, 2wv+1} of the 16x128 output
    int lr = lane & 15;
    int lk = (lane >> 4) * 8;
    bf16x8 a[4];
#pragma unroll
    for (int kk = 0; kk < 4; ++kk)
        a[kk] = *(const bf16x8*)&lds[lr][kk * 32 + lk];
    f32x4 acc[2] = {};
#pragma unroll
    for (int c2 = 0; c2 < 2; ++c2) {
        int c = wv * 2 + c2;
#pragma unroll
        for (int kk = 0; kk < 4; ++kk) {
            bf16x8 b = *(const bf16x8*)&WT[(size_t)(c * 16 + lr) * 128 + kk * 32 + lk];
            acc[c2] = __builtin_amdgcn_mfma_f32_16x16x32_bf16(a[kk], b, acc[c2], 0, 0, 0);
        }
    }
#pragma unroll
    for (int r = 0; r < 4; ++r) {
        int n2 = blockIdx.x * 16 + (lane >> 4) * 4 + r;
        if (n2 < n) {
            float sc = dinv[n2];
            O[(size_t)n2 * 128 + (wv * 2 + 0) * 16 + lr] = f2bf(acc[0][r] * sc);
            O[(size_t)n2 * 128 + (wv * 2 + 1) * 16 + lr] = f2bf(acc[1][r] * sc);
        }
    }
}

// ---- fused agg2(+b2+relu) -> LDS -> @WLT * dinv -> fp32 P[n][16] (wave 0 does the 16-wide tile) ----
__global__ __launch_bounds__(256) void k_agg_gemmP(const uint4* __restrict__ Hw,
                                                   const int* __restrict__ rowptr,
                                                   const float2* __restrict__ csr,
                                                   const float* __restrict__ bias,
                                                   const unsigned short* __restrict__ WLT,
                                                   const float* __restrict__ dinv,
                                                   float* __restrict__ P, int n) {
    __shared__ __align__(16) unsigned short lds[16][132];
    AGG_BODY(bias)
    if (wv == 0) {
        int lr = lane & 15;
        int lk = (lane >> 4) * 8;
        f32x4 acc = {};
#pragma unroll
        for (int kk = 0; kk < 4; ++kk) {
            bf16x8 a = *(const bf16x8*)&lds[lr][kk * 32 + lk];
            bf16x8 b = *(const bf16x8*)&WLT[(size_t)lr * 128 + kk * 32 + lk];
            acc = __builtin_amdgcn_mfma_f32_16x16x32_bf16(a, b, acc, 0, 0, 0);
        }
#pragma unroll
        for (int r = 0; r < 4; ++r) {
            int n2 = blockIdx.x * 16 + (lane >> 4) * 4 + r;
            if (n2 < n) P[(size_t)n2 * 16 + lr] = acc[r] * dinv[n2];
        }
    }
}
#undef FMA8
#undef AGG_BODY

// ---------------- fused layer-3 agg + pool (linear path): per-graph edge-sum of P ----------------
__device__ __forceinline__ int lower_bound_i(const int* a, int n, int key) {
    int lo = 0, hi = n;
    while (lo < hi) { int mid = (lo + hi) >> 1; if (a[mid] < key) lo = mid + 1; else hi = mid; }
    return lo;
}

// PB blocks per graph; each walks a contiguous edge subrange (batch sorted => graph edges contiguous)
__global__ __launch_bounds__(256) void k_agg_pool(const float4* __restrict__ P4,
                                                  const int* __restrict__ rowptr,
                                                  const float2* __restrict__ csr,
                                                  const int* __restrict__ batch,
                                                  int n, float* __restrict__ partial) {
    int g = blockIdx.x >> 2, part = blockIdx.x & (PB - 1);
    int start = lower_bound_i(batch, n, g);
    int end   = lower_bound_i(batch, n, g + 1);
    int cn = end - start;
    int ns = start + (cn * part) / PB;
    int ne = start + (cn * (part + 1)) / PB;
    int es = rowptr[ns], ee = rowptr[ne];
    int t = threadIdx.x, grp = t >> 2, sl4 = t & 3;   // 64 groups x 4 lanes
    float a0 = 0.f, a1 = 0.f, a2 = 0.f, a3 = 0.f;
    int i = es + grp;
    for (; i + 64 < ee; i += 128) {
        float2 p0 = csr[i], p1 = csr[i + 64];
        float4 v0 = P4[(size_t)__float_as_int(p0.x) * 4 + sl4];
        float4 v1 = P4[(size_t)__float_as_int(p1.x) * 4 + sl4];
        a0 += v0.x * p0.y; a1 += v0.y * p0.y; a2 += v0.z * p0.y; a3 += v0.w * p0.y;
        a0 += v1.x * p1.y; a1 += v1.y * p1.y; a2 += v1.z * p1.y; a3 += v1.w * p1.y;
    }
    if (i < ee) {
        float2 pp = csr[i];
        float4 v = P4[(size_t)__float_as_int(pp.x) * 4 + sl4];
        a0 += v.x * pp.y; a1 += v.y * pp.y; a2 += v.z * pp.y; a3 += v.w * pp.y;
    }
    __shared__ float red[64][20];
    *(float4*)&red[grp][sl4 * 4] = make_float4(a0, a1, a2, a3);
    __syncthreads();
    if (t < 16) {
        float s = 0.f;
        for (int k2 = 0; k2 < 64; ++k2) s += red[k2][t];
        partial[(size_t)blockIdx.x * 16 + t] = s;
    }
}

// final: reduce PB partials, /cnt, + b3@Wlin + blin
__global__ void k_poolfin(const float* __restrict__ partial, const int* __restrict__ batch,
                          const float* __restrict__ b3, const float* __restrict__ Wlin,
                          const float* __restrict__ blin, float* __restrict__ out, int n) {
    int g = blockIdx.x, t = threadIdx.x;
    if (t >= 16) return;
    int start = lower_bound_i(batch, n, g);
    int end   = lower_bound_i(batch, n, g + 1);
    int cn = end - start;
    float s = partial[(size_t)(g * PB + 0) * 16 + t] + partial[(size_t)(g * PB + 1) * 16 + t]
            + partial[(size_t)(g * PB + 2) * 16 + t] + partial[(size_t)(g * PB + 3) * 16 + t];
    float bw = 0.f;
    for (int ch = 0; ch < 128; ++ch) bw += b3[ch] * Wlin[ch * 16 + t];
    out[g * 16 + t] = (cn > 0) ? s / (float)cn + bw + blin[t] : blin[t];
}

// ---------------- host ----------------
extern "C" void kernel_launch(void* const* d_in, const int* in_sizes, int n_in,
                              void* d_out, int out_size, void* d_ws, size_t ws_size,
                              hipStream_t stream) {
    const float* x    = (const float*)d_in[0];
    const int*   ei   = (const int*)d_in[1];
    const float* ew   = (const float*)d_in[2];
    const int*   batch= (const int*)d_in[3];
    const float* W1   = (const float*)d_in[4];
    const float* b1   = (const float*)d_in[5];
    const float* W2   = (const float*)d_in[6];
    const float* b2   = (const float*)d_in[7];
    const float* W3   = (const float*)d_in[8];
    const float* b3   = (const float*)d_in[9];
    const float* Wlin = (const float*)d_in[10];
    const float* blin = (const float*)d_in[11];
    float* out = (float*)d_out;

    int n  = in_sizes[0] / 128;
    int E  = in_sizes[2];
    int e2 = E + n;
    int G  = out_size / 16;
    const int* row = ei;
    const int* col = ei + E;

    int nbkt = (n + 255) >> 8;          // 256 nodes per bucket
    int M    = nbkt * NB;

    char* ws = (char*)d_ws;
    size_t off = 0;
    auto alloc = [&](size_t bytes) -> void* {
        void* p = ws + off;
        off = (off + bytes + 255) & ~255UL;
        return p;
    };
    // regionA: csrR (e2*8B) during pre; bf16 m2 (n*256B) after k_build
    size_t rawBytes = (size_t)e2 * 8;
    size_t hBytes   = (size_t)n * 128 * 2;
    void* regionA = alloc(rawBytes > hBytes ? rawBytes : hBytes);
    uint2*  csrR  = (uint2*)regionA;
    unsigned short* bufM2 = (unsigned short*)regionA;       // aliases csrR after k_build
    unsigned short* bufM1 = (unsigned short*)alloc((size_t)n * 128 * 2);
    float2* csrF  = (float2*)alloc((size_t)e2 * 8);
    int*    cntA  = (int*)  alloc((size_t)M * 4);
    int*    S     = (int*)  alloc((size_t)M * 4);
    int*    bsum  = (int*)  alloc(4096);
    float*  dinv  = (float*)alloc((size_t)n * 4);
    int*    rowptr= (int*)  alloc((size_t)(n + 1) * 4);
    unsigned short* WT1 = (unsigned short*)alloc(128 * 128 * 2);
    unsigned short* WT2 = (unsigned short*)alloc(128 * 128 * 2);
    unsigned short* WLT = (unsigned short*)alloc(16 * 128 * 2);
    float*  P       = (float*)alloc((size_t)n * 16 * 4);
    float*  partial = (float*)alloc((size_t)G * PB * 16 * 4);
    (void)ws_size;

    int per = (e2 + NB - 1) / NB;
    int nbScan = (M + SCAN_E - 1) / SCAN_E;   // <= 256 for n <= 131072

    // fused weight prep + dst histogram (all independent)
    k_wt3_hist<<<136 + NB, 256, 0, stream>>>(W1, W2, W3, Wlin, WT1, WT2, WLT,
                                             col, E, e2, per, cntA, nbkt);
    k_scan_a<<<nbScan, SCAN_T, 0, stream>>>(cntA, M, S, bsum);
    k_scan_b<<<1, 256, 0, stream>>>(bsum, nbScan);
    k_scatter1<<<NB, 256, 0, stream>>>(row, col, ew, E, e2, per, S, bsum, csrR, nbkt);
    k_build<<<nbkt, 256, 0, stream>>>(csrR, S, bsum, n, e2, csrF, dinv, rowptr, nbkt);

    int gb = (n + 63) / 64;
    int ab = (n + 15) / 16;
    k_gemm_mfma<<<gb, 256, 0, stream>>>(x, WT1, dinv, bufM1, n);
    k_agg_gemm<<<ab, 256, 0, stream>>>((const uint4*)bufM1, rowptr, csrF, b1, WT2, dinv, bufM2, n);
    k_agg_gemmP<<<ab, 256, 0, stream>>>((const uint4*)bufM2, rowptr, csrF, b2, WLT, dinv, P, n);
    k_agg_pool<<<G * PB, 256, 0, stream>>>((const float4*)P, rowptr, csrF, batch, n, partial);
    k_poolfin<<<G, 64, 0, stream>>>(partial, batch, b3, Wlin, blin, out, n);
}